// Round 10
// baseline (232.116 us; speedup 1.0000x reference)
//
#include <hip/hip_runtime.h>
#include <hip/hip_bf16.h>
#include <stdint.h>

typedef __bf16 bf16_t;
typedef bf16_t bf16x8 __attribute__((ext_vector_type(8)));
typedef bf16_t bf16x4 __attribute__((ext_vector_type(4)));
typedef float f32x4 __attribute__((ext_vector_type(4)));

#define BM 128
#define BN 128
#define BK 32

// async global->LDS, 16B per lane. LDS dst is wave-uniform base + lane*16;
// the GLOBAL source may be arbitrary per-lane (used for the bank swizzle).
__device__ __forceinline__ void gload_lds16(const void* g, void* l) {
    __builtin_amdgcn_global_load_lds(
        (const __attribute__((address_space(1))) void*)(uintptr_t)g,
        (__attribute__((address_space(3))) void*)(uintptr_t)l,
        16, 0, 0);
}

// ---------------------------------------------------------------------------
// NT-GEMM body, 128x128 tile, 4 waves (2x2), 4x4 MFMA 16x16x32 per wave.
// C[m,n] = scale * sum_{k0beg<=k<k1end} A[m,k]*B[n,k].
// LDS bank swizzle (r6-verified, conflicts 6.3M->0): slot s of a row holds
// global k-chunk (s-(row>>1))&3; staging compensates on the global side.
// __shared__ passed in so multiple instantiations share one allocation.
// EPI: 0 = bf16 row-major store                        (gemm1 K|Q)
//      2 = f32 store or atomicAdd, divided by rs[row]  (gemm3, split-K)
//      3 = exp(v) causal-masked bf16 store + atomic row-sum into rs  (qk)
//      4 = bf16 transposed into Vt[b][d][s]            (gemm1 V)
// ---------------------------------------------------------------------------
template <int EPI>
__device__ __forceinline__ void gemm_body(
    bf16_t* __restrict__ As, bf16_t* __restrict__ Bs,
    const bf16_t* __restrict__ A, long lda,
    const bf16_t* __restrict__ B, long ldb,
    void* __restrict__ Cv, long ldc,
    int k0beg, int k1end, float scale, int m0, int n0,
    float* __restrict__ rs, int use_atomic)
{
    const int tid = threadIdx.x;
    const int wid = tid >> 6, lane = tid & 63;
    const int wr = wid >> 1, wc = wid & 1;
    const int hw = lane >> 4, ln = lane & 15;

    // staging: 512 chunks of 16B per matrix, 2 per thread; swizzled source.
    const bf16_t *srcA[2], *srcB[2];
#pragma unroll
    for (int i = 0; i < 2; i++) {
        const int c = tid + i * 256;
        const int row = c >> 2;
        const int j = ((c & 3) - (row >> 1)) & 3;   // global k-chunk for this slot
        srcA[i] = A + (size_t)(m0 + row) * lda + j * 8;
        srcB[i] = B + (size_t)(n0 + row) * ldb + j * 8;
    }

    f32x4 acc[4][4] = {};

    for (int k0 = k0beg; k0 < k1end; k0 += BK) {
        gload_lds16(srcA[0] + k0, &As[wid * 512]);
        gload_lds16(srcA[1] + k0, &As[2048 + wid * 512]);
        gload_lds16(srcB[0] + k0, &Bs[wid * 512]);
        gload_lds16(srcB[1] + k0, &Bs[2048 + wid * 512]);
        __syncthreads();

        bf16x8 af[4], bfr[4];
#pragma unroll
        for (int t = 0; t < 4; t++) {
            const int r  = wr * 64 + t * 16 + ln;
            const int rb = wc * 64 + t * 16 + ln;
            af[t]  = *(const bf16x8*)&As[r  * BK + (((hw + (r  >> 1)) & 3) * 8)];
            bfr[t] = *(const bf16x8*)&Bs[rb * BK + (((hw + (rb >> 1)) & 3) * 8)];
        }
#pragma unroll
        for (int ti = 0; ti < 4; ti++)
#pragma unroll
            for (int tj = 0; tj < 4; tj++)
                acc[ti][tj] = __builtin_amdgcn_mfma_f32_16x16x32_bf16(
                    af[ti], bfr[tj], acc[ti][tj], 0, 0, 0);
        __syncthreads();
    }

    // epilogue: C/D layout col=lane&15, row=(lane>>4)*4+reg (m89-verified)
#pragma unroll
    for (int ti = 0; ti < 4; ti++) {
        const int rbase = m0 + wr * 64 + ti * 16 + hw * 4;
        f32x4 inv4;
        if (EPI == 2) {
            const float4 r4 = *(const float4*)&rs[rbase];
            inv4[0] = 1.0f / r4.x; inv4[1] = 1.0f / r4.y;
            inv4[2] = 1.0f / r4.z; inv4[3] = 1.0f / r4.w;
        }
        float part[4] = {0.f, 0.f, 0.f, 0.f};   // EPI 3: per-row partial sums
#pragma unroll
        for (int tj = 0; tj < 4; tj++) {
            const int col = n0 + wc * 64 + tj * 16 + ln;
            if (EPI == 4) {
                // transposed bf16: 4 consecutive rows -> 8B contiguous in Vt
                const int bb = rbase >> 11;
                const int s  = rbase & 2047;
                const int d  = col - 2048;
                bf16x4 o;
#pragma unroll
                for (int rg = 0; rg < 4; rg++) o[rg] = (bf16_t)acc[ti][tj][rg];
                *(bf16x4*)&((bf16_t*)Cv)[(size_t)bb * 2097152 + (size_t)d * 2048 + s] = o;
            } else {
#pragma unroll
                for (int rg = 0; rg < 4; rg++) {
                    const size_t idx = (size_t)(rbase + rg) * ldc + col;
                    if (EPI == 0) {
                        ((bf16_t*)Cv)[idx] = (bf16_t)(acc[ti][tj][rg]);
                    } else if (EPI == 2) {
                        const float v = acc[ti][tj][rg] * inv4[rg];
                        if (use_atomic) atomicAdd(&((float*)Cv)[idx], v);
                        else            ((float*)Cv)[idx] = v;
                    } else {  // EPI 3: exp + causal mask + row-sum
                        const float e = (col <= rbase + rg)
                                      ? __expf(acc[ti][tj][rg] * scale) : 0.0f;
                        part[rg] += e;
                        ((bf16_t*)Cv)[idx] = (bf16_t)e;
                    }
                }
            }
        }
        if (EPI == 3) {
#pragma unroll
            for (int rg = 0; rg < 4; rg++) {
                float p = part[rg];
                p += __shfl_xor(p, 1, 64);
                p += __shfl_xor(p, 2, 64);
                p += __shfl_xor(p, 4, 64);
                p += __shfl_xor(p, 8, 64);
                if (ln == 0) atomicAdd(&rs[rbase + rg], p);
            }
        }
    }
}

// ---------------------------------------------------------------------------
// GEMM1: [K|Q] = x*W^T row-major into QKVb (8192x2048); V written transposed
// into Vt[b][d][s]. M=8192, N=3072 (24 nblk of 128), K=1024. grid 1536.
// XCD-pinned swizzle (r5-verified: FETCH 138->49 MB).
// ---------------------------------------------------------------------------
__global__ __launch_bounds__(256) void gemm1_qkv(
    const bf16_t* __restrict__ xb, const bf16_t* __restrict__ Wb,
    bf16_t* __restrict__ QKVb, bf16_t* __restrict__ Vt)
{
    __shared__ __align__(16) bf16_t As[BM * BK];
    __shared__ __align__(16) bf16_t Bs[BN * BK];
    const int lin = blockIdx.x;            // 0..1535
    const int xcd = lin & 7;
    const int j   = lin >> 3;              // 0..191
    const int p   = j >> 6;                // 0..2
    const int w   = j & 63;                // 0..63
    const int mblk = xcd * 8 + (w >> 3);   // 0..63
    const int nblk = p * 8 + (w & 7);      // 0..23
    const int m0 = mblk * BM, n0 = nblk * BN;
    if (nblk < 16)
        gemm_body<0>(As, Bs, xb, 1024, Wb, 1024, QKVb, 2048,
                     0, 1024, 1.0f, m0, n0, nullptr, 0);
    else
        gemm_body<4>(As, Bs, xb, 1024, Wb, 1024, Vt, 2048,
                     0, 1024, 1.0f, m0, n0, nullptr, 0);
}

// ---------------------------------------------------------------------------
// GEMM2+exp: E = exp(scale*Q K^T) per batch, causal-masked, bf16; row sums
// accumulated into rowsum (f32, pre-zeroed). 544 blocks, heavy-first.
// ---------------------------------------------------------------------------
__global__ __launch_bounds__(256) void qk_gemm(
    const bf16_t* __restrict__ QKVb, bf16_t* __restrict__ E,
    float* __restrict__ rowsum)
{
    __shared__ __align__(16) bf16_t As[BM * BK];
    __shared__ __align__(16) bf16_t Bs[BN * BK];
    const int b = blockIdx.x & 3;
    int rem = blockIdx.x >> 2;             // 0..135
    int my = 15, nx = 0;
#pragma unroll
    for (int m = 15; m >= 0; --m) {        // heavy strips first
        if (rem < m + 1) { my = m; nx = rem; break; }
        rem -= m + 1;
    }
    const bf16_t* base = QKVb + (size_t)b * (2048L * 2048);
    gemm_body<3>(As, Bs,
                 base + 1024, 2048,        // Q
                 base, 2048,               // K
                 E + (size_t)b * (2048L * 2048), 2048,
                 0, 1024, 0.03125f, my * BM, nx * BN,
                 rowsum + b * 2048, 0);
}

// ---------------------------------------------------------------------------
// GEMM3: out = (E * Vt^T)/rowsum per batch -> f32. Split-K equalized:
// strips 0..7 single chunk (plain store); strips 8..15 split at K=1024 into
// two chunks (atomicAdd into pre-zeroed out). 192 items/batch * 4 = 768
// blocks = one residency round at 3 blocks/CU; all chunks <= 32 K-iters.
// ---------------------------------------------------------------------------
__global__ __launch_bounds__(256) void gemm3_pv(
    const bf16_t* __restrict__ E, const bf16_t* __restrict__ Vt,
    const float* __restrict__ rowsum, float* __restrict__ out)
{
    __shared__ __align__(16) bf16_t As[BM * BK];
    __shared__ __align__(16) bf16_t Bs[BN * BK];
    const int b = blockIdx.x & 3;
    const int item = blockIdx.x >> 2;      // 0..191
    int s, nx, k0, k1, at;
    if (item < 64) {                       // strips 0..7: single chunk
        s = item >> 3; nx = item & 7;
        k0 = 0; k1 = (s + 1) * 128; at = 0;
    } else {                               // strips 8..15: two chunks, atomic
        const int q = item - 64;           // 0..127
        s = 8 + (q >> 4);
        const int r = q & 15;
        const int ci = r >> 3;
        nx = r & 7;
        k0 = ci ? 1024 : 0;
        k1 = ci ? (s + 1) * 128 : 1024;
        at = 1;
    }
    gemm_body<2>(As, Bs,
                 E + (size_t)b * (2048L * 2048), 2048,
                 Vt + (size_t)b * (1024L * 2048), 2048,
                 out + (size_t)b * (2048L * 1024), 1024,
                 k0, k1, 1.0f, s * BM, nx * BN,
                 (float*)rowsum + b * 2048, at);
}

// ---------------------------------------------------------------------------
// Merged prep: [0,8192) cast x; [8192,11264) cast W; [11264,11272) zero
// rowsum; [11272,15368) zero out rows >=1024 (split-K atomic targets).
__global__ __launch_bounds__(256) void cast_all(
    const float* __restrict__ x,
    const float* __restrict__ Wk, const float* __restrict__ Wq,
    const float* __restrict__ Wv,
    bf16_t* __restrict__ xb, bf16_t* __restrict__ Wb,
    float* __restrict__ rowsum, float* __restrict__ out)
{
    const int blk = blockIdx.x;
    if (blk >= 11272) {
        const int v = blk - 11272;         // 0..4095
        const size_t off = (size_t)(v >> 10) * 2097152 + 1048576
                         + (size_t)(v & 1023) * 1024 + (size_t)threadIdx.x * 4;
        *(float4*)(out + off) = make_float4(0.f, 0.f, 0.f, 0.f);
        return;
    }
    if (blk >= 11264) {
        const size_t i = ((size_t)(blk - 11264) * 256 + threadIdx.x) * 4;
        *(float4*)(rowsum + i) = make_float4(0.f, 0.f, 0.f, 0.f);
        return;
    }
    const float* src;
    bf16_t* dst;
    if (blk < 8192) {
        const size_t i = ((size_t)blk * 256 + threadIdx.x) * 4;
        src = x + i;
        dst = xb + i;
    } else {
        const size_t j = ((size_t)(blk - 8192) * 256 + threadIdx.x) * 4;
        dst = Wb + j;
        if (j < (size_t)1048576)      src = Wk + j;
        else if (j < (size_t)2097152) src = Wq + (j - 1048576);
        else                          src = Wv + (j - 2097152);
    }
    const float4 v = *(const float4*)src;
    bf16x4 o;
    o.x = (bf16_t)v.x; o.y = (bf16_t)v.y; o.z = (bf16_t)v.z; o.w = (bf16_t)v.w;
    *(bf16x4*)dst = o;
}

// ---------------------------------------------------------------------------
extern "C" void kernel_launch(void* const* d_in, const int* in_sizes, int n_in,
                              void* d_out, int out_size, void* d_ws, size_t ws_size,
                              hipStream_t stream)
{
    const float* x  = (const float*)d_in[0];
    const float* Wk = (const float*)d_in[1];
    const float* Wq = (const float*)d_in[2];
    const float* Wv = (const float*)d_in[3];
    char* ws = (char*)d_ws;

    // ws layout (81 MB used):
    //   [0,32)   QKVb bf16 8192x2048  ([K|Q] columns only; V goes to Vt)
    //   [32,48)  Vt   bf16 4 x 1024x2048 (written transposed by GEMM1)
    //   [48,64)  xb   bf16 8192x1024   (dead after GEMM1)
    //   [64,70)  Wb   bf16 3072x1024   (dead after GEMM1)
    //   [48,80)  E    bf16 4 x 2048x2048 exp-logits (aliases xb+Wb, both dead)
    //   [80,81)  rowsum f32 4x2048 (zeroed by cast_all)
    bf16_t* QKVb   = (bf16_t*)(ws);
    bf16_t* Vt     = (bf16_t*)(ws + ((size_t)32 << 20));
    bf16_t* xb     = (bf16_t*)(ws + ((size_t)48 << 20));
    bf16_t* Wb     = (bf16_t*)(ws + ((size_t)64 << 20));
    bf16_t* E      = (bf16_t*)(ws + ((size_t)48 << 20));
    float*  rowsum = (float*)(ws + ((size_t)80 << 20));
    float*  out    = (float*)d_out;

    // 1. cast inputs to bf16 + zero rowsum + zero out rows >=1024
    cast_all<<<15368, 256, 0, stream>>>(x, Wk, Wq, Wv, xb, Wb, rowsum, out);

    // 2. GEMM1 (XCD-pinned swizzle; V stored transposed -> no transpose kernel)
    gemm1_qkv<<<1536, 256, 0, stream>>>(xb, Wb, QKVb, Vt);

    // 3. GEMM2: causal exp(QK^T) -> bf16 E + atomic row sums (no softmax kernel)
    qk_gemm<<<544, 256, 0, stream>>>(QKVb, E, rowsum);

    // 4. GEMM3: split-K equalized (all chunks <= 32 K-iters), 768 blocks
    gemm3_pv<<<768, 256, 0, stream>>>(E, Vt, rowsum, out);
}